// Round 9
// baseline (5918.468 us; speedup 1.0000x reference)
//
#include <hip/hip_runtime.h>
#include <cstdint>
#include <cstddef>

#define B_SZ   4
#define N_PTS  16384
#define M_CENT 2048
#define NSAMP  32
#define C_IN   64
#define H1_DIM 64
#define H2_DIM 128
#define FPS_T  1024
#define NCL    256                // clusters of 64 points
#define NCELL  512                // 8x8x8 sort cells
#define H0_STR 68                 // 67 channels padded to 68 for 16B-aligned float4

// u64 max with neighbor fetched via DPP (invalid lanes keep self = identity
// under max). HW-verified rounds 3-8.
template <int CTRL>
__device__ __forceinline__ unsigned long long kmax_dpp(unsigned long long k) {
  const int lo  = (int)(unsigned)(k & 0xFFFFFFFFULL);
  const int hi  = (int)(unsigned)(k >> 32);
  const int olo = __builtin_amdgcn_update_dpp(lo, lo, CTRL, 0xF, 0xF, false);
  const int ohi = __builtin_amdgcn_update_dpp(hi, hi, CTRL, 0xF, 0xF, false);
  const unsigned long long o =
      ((unsigned long long)(unsigned)ohi << 32) | (unsigned)olo;
  return (o > k) ? o : k;
}

// ---------------------------------------------------------------------------
// K1: EXACT spatially-pruned FPS. One 1024-thr block per batch.
// LESSON (r0-r8): the brute scan of 16384 pts/iter is issue-saturated at
// ~1.6 us/iter regardless of residency/instruction-mix/occupancy -- the only
// lever left is not scanning. fmin is exactly associative: skipping mins
// that are PROVABLY identity (d2 >= pd for every point of a cluster) leaves
// every pd and every argmax bit-identical to the reference.
// Structure: counting-sort points by 8x8x8 cell -> 256 clusters of 64 sorted
// slots. Per cluster: bounding sphere (center, inflated radius) + exact key
// ckey = max over its points of (pd_bits<<32 | N-origidx). Per iteration:
//  A) lane<16 tests its cluster (c = lane*16+wave): skip iff gap=dq-rad > 0
//     and gap^2 > ub*1.001+1e-5 (margins >> f32 eval error => conservative).
//     Cluster holding the just-picked point has dq<=rad -> always updates,
//     so its pd drops to 0 (never re-picked).
//  B) wave updates its flagged clusters: 64 lanes, gather coords from
//     L2-hot xyz, exact d2 (numpy op order, no FMA), fmin into LDS pd,
//     6-lvl DPP -> new exact ckey.
//  C) global argmax = DPP-max over the 256 exact ckeys (skipped clusters'
//     keys are current since their pds are unchanged) -> same u64 tie-break
//     (max dist, min orig idx) as rounds 3-8.
// Sort order inside cells is atomic-nondeterministic -> only the skip
// PATTERN varies; outputs stay bit-exact (skips are identity ops).
// ---------------------------------------------------------------------------
__global__ __launch_bounds__(FPS_T, 4) void fps_kernel(const float* __restrict__ xyz,
                                                       float* __restrict__ out_xyz) {
#pragma clang fp contract(off)
  const int b    = blockIdx.x;
  const int t    = threadIdx.x;
  const int lane = t & 63;
  const int wave = t >> 6;           // 16 waves
  const float* bx = xyz + (size_t)b * N_PTS * 3;
  float* ox = out_xyz + (size_t)b * M_CENT * 3;

  __shared__ float              pd_l[N_PTS];       // 64K  running min-dist^2
  __shared__ unsigned short     sidx[N_PTS];       // 32K  sorted slot -> orig idx
  __shared__ float              cctr[NCL * 3];     // 3K   cluster centers
  __shared__ float              crad[NCL];         // 1K   inflated radii
  __shared__ unsigned long long ckey[NCL];         // 2K   exact cluster keys
  __shared__ int                hist[NCELL];       // 2K
  __shared__ int                offs[NCELL];       // 2K
  __shared__ unsigned long long s_key[2][16];
  __shared__ float              s_part[16][6];
  __shared__ float              s_bbox[6];

  // ---- preprocess 1: bounding box ----
  {
    float mnx = 1e30f, mny = 1e30f, mnz = 1e30f;
    float mxx = -1e30f, mxy = -1e30f, mxz = -1e30f;
    for (int i = t; i < N_PTS; i += FPS_T) {
      const float x = bx[i * 3 + 0], y = bx[i * 3 + 1], z = bx[i * 3 + 2];
      mnx = fminf(mnx, x); mxx = fmaxf(mxx, x);
      mny = fminf(mny, y); mxy = fmaxf(mxy, y);
      mnz = fminf(mnz, z); mxz = fmaxf(mxz, z);
    }
    for (int off = 32; off >= 1; off >>= 1) {
      mnx = fminf(mnx, __shfl_xor(mnx, off)); mxx = fmaxf(mxx, __shfl_xor(mxx, off));
      mny = fminf(mny, __shfl_xor(mny, off)); mxy = fmaxf(mxy, __shfl_xor(mxy, off));
      mnz = fminf(mnz, __shfl_xor(mnz, off)); mxz = fmaxf(mxz, __shfl_xor(mxz, off));
    }
    if (lane == 0) {
      s_part[wave][0] = mnx; s_part[wave][1] = mny; s_part[wave][2] = mnz;
      s_part[wave][3] = mxx; s_part[wave][4] = mxy; s_part[wave][5] = mxz;
    }
    __syncthreads();
    if (t == 0) {
      float v0 = 1e30f, v1 = 1e30f, v2 = 1e30f, v3 = -1e30f, v4 = -1e30f, v5 = -1e30f;
      for (int w = 0; w < 16; ++w) {
        v0 = fminf(v0, s_part[w][0]); v1 = fminf(v1, s_part[w][1]);
        v2 = fminf(v2, s_part[w][2]); v3 = fmaxf(v3, s_part[w][3]);
        v4 = fmaxf(v4, s_part[w][4]); v5 = fmaxf(v5, s_part[w][5]);
      }
      s_bbox[0] = v0; s_bbox[1] = v1; s_bbox[2] = v2;
      s_bbox[3] = 8.0f / fmaxf(v3 - v0, 1e-20f);   // inv widths
      s_bbox[4] = 8.0f / fmaxf(v4 - v1, 1e-20f);
      s_bbox[5] = 8.0f / fmaxf(v5 - v2, 1e-20f);
    }
    if (t < NCELL) hist[t] = 0;
    __syncthreads();
  }
  const float bb0 = s_bbox[0], bb1 = s_bbox[1], bb2 = s_bbox[2];
  const float iw0 = s_bbox[3], iw1 = s_bbox[4], iw2 = s_bbox[5];

  // ---- preprocess 2: histogram, prefix, scatter (counting sort by cell) ----
  for (int i = t; i < N_PTS; i += FPS_T) {
    const float x = bx[i * 3 + 0], y = bx[i * 3 + 1], z = bx[i * 3 + 2];
    int qx = (int)((x - bb0) * iw0); qx = qx > 7 ? 7 : qx;
    int qy = (int)((y - bb1) * iw1); qy = qy > 7 ? 7 : qy;
    int qz = (int)((z - bb2) * iw2); qz = qz > 7 ? 7 : qz;
    atomicAdd(&hist[(qx << 6) | (qy << 3) | qz], 1);
  }
  __syncthreads();
  if (t < NCELL) {
    int s = 0;
    for (int i = 0; i < t; ++i) s += hist[i];
    offs[t] = s;
  }
  __syncthreads();
  for (int i = t; i < N_PTS; i += FPS_T) {
    const float x = bx[i * 3 + 0], y = bx[i * 3 + 1], z = bx[i * 3 + 2];
    int qx = (int)((x - bb0) * iw0); qx = qx > 7 ? 7 : qx;
    int qy = (int)((y - bb1) * iw1); qy = qy > 7 ? 7 : qy;
    int qz = (int)((z - bb2) * iw2); qz = qz > 7 ? 7 : qz;
    const int slot = atomicAdd(&offs[(qx << 6) | (qy << 3) | qz], 1);
    sidx[slot] = (unsigned short)i;
  }
  for (int i = t; i < N_PTS; i += FPS_T) pd_l[i] = 1e10f;  // BIG
  __syncthreads();

  // ---- preprocess 3: cluster bounding spheres (wave w owns c == w mod 16) ----
  for (int c = wave; c < NCL; c += 16) {
    const int oi = (int)sidx[c * 64 + lane];
    const float x = bx[oi * 3 + 0], y = bx[oi * 3 + 1], z = bx[oi * 3 + 2];
    float mnx = x, mxx = x, mny = y, mxy = y, mnz = z, mxz = z;
    for (int off = 32; off >= 1; off >>= 1) {
      mnx = fminf(mnx, __shfl_xor(mnx, off)); mxx = fmaxf(mxx, __shfl_xor(mxx, off));
      mny = fminf(mny, __shfl_xor(mny, off)); mxy = fmaxf(mxy, __shfl_xor(mxy, off));
      mnz = fminf(mnz, __shfl_xor(mnz, off)); mxz = fmaxf(mxz, __shfl_xor(mxz, off));
    }
    const float ctx = (mnx + mxx) * 0.5f, cty = (mny + mxy) * 0.5f, ctz = (mnz + mxz) * 0.5f;
    const float ddx = x - ctx, ddy = y - cty, ddz = z - ctz;
    float dd = sqrtf(ddx * ddx + ddy * ddy + ddz * ddz);
    for (int off = 32; off >= 1; off >>= 1) dd = fmaxf(dd, __shfl_xor(dd, off));
    if (lane == 0) {
      cctr[c * 3 + 0] = ctx; cctr[c * 3 + 1] = cty; cctr[c * 3 + 2] = ctz;
      crad[c] = dd * 1.0002f + 1e-6f;                    // conservative inflation
      ckey[c] = 0x501502F900000001ULL;                   // (bits(1e10)<<32)|1
    }
  }
  __syncthreads();

  // ---- main loop ----
  int cur = 0;  // reference idx0 = 0 (original index)
  for (int m = 0; m < M_CENT; ++m) {
    const int curs = __builtin_amdgcn_readfirstlane(cur);
    const float cx = bx[curs * 3 + 0];
    const float cy = bx[curs * 3 + 1];
    const float cz = bx[curs * 3 + 2];
    if (t == 0) { ox[m * 3 + 0] = cx; ox[m * 3 + 1] = cy; ox[m * 3 + 2] = cz; }
    if (m == M_CENT - 1) break;

    // Phase A: skip test, one cluster per lane (<16): c = lane*16 + wave
    bool upd = false;
    if (lane < 16) {
      const int c = lane * 16 + wave;
      const float qx = cctr[c * 3 + 0] - cx;
      const float qy = cctr[c * 3 + 1] - cy;
      const float qz = cctr[c * 3 + 2] - cz;
      const float dq  = sqrtf(qx * qx + qy * qy + qz * qz);
      const float gap = dq - crad[c];
      const float ub  = __uint_as_float((unsigned)(ckey[c] >> 32));
      upd = !((gap > 0.0f) && (gap * gap > ub * 1.001f + 1e-5f));
    }
    unsigned long long mask = __ballot(upd);

    // Phase B: update flagged clusters (whole wave per cluster)
    while (mask) {
      const int s = __builtin_ctzll(mask);
      mask &= mask - 1;
      const int c    = s * 16 + wave;
      const int slot = c * 64 + lane;
      const int oi   = (int)sidx[slot];
      const float x = bx[oi * 3 + 0], y = bx[oi * 3 + 1], z = bx[oi * 3 + 2];
      const float dx = x - cx, dy = y - cy, dz = z - cz;
      const float d2 = (dx * dx + dy * dy) + dz * dz;   // numpy order, no FMA
      const float nd = fminf(pd_l[slot], d2);
      pd_l[slot] = nd;
      unsigned long long key = ((unsigned long long)__float_as_uint(nd) << 32)
                             | (unsigned int)(N_PTS - oi);
      key = kmax_dpp<0x111>(key);
      key = kmax_dpp<0x112>(key);
      key = kmax_dpp<0x114>(key);
      key = kmax_dpp<0x118>(key);
      key = kmax_dpp<0x142>(key);
      key = kmax_dpp<0x143>(key);
      if (lane == 63) ckey[c] = key;
    }

    // Phase C: global argmax over 256 exact cluster keys.
    // Own-slice reduce (no barrier needed: slice written only by this wave).
    unsigned long long wk = (lane < 16) ? ckey[lane * 16 + wave] : 0ULL;
    wk = kmax_dpp<0x111>(wk);
    wk = kmax_dpp<0x112>(wk);
    wk = kmax_dpp<0x114>(wk);
    wk = kmax_dpp<0x118>(wk);
    wk = kmax_dpp<0x142>(wk);
    wk = kmax_dpp<0x143>(wk);
    const int p = m & 1;
    if (lane == 63) s_key[p][wave] = wk;
    __syncthreads();
    unsigned long long k2 = s_key[p][lane & 15];
    k2 = kmax_dpp<0x111>(k2);
    k2 = kmax_dpp<0x112>(k2);
    k2 = kmax_dpp<0x114>(k2);
    k2 = kmax_dpp<0x118>(k2);
    const int lo15 = __builtin_amdgcn_readlane((int)(unsigned)(k2 & 0xFFFFFFFFULL), 15);
    cur = N_PTS - lo15;
  }
}

// ---------------------------------------------------------------------------
// K2: Ball query. One wave per centroid: ballot + prefix popcount appends the
// first 32 in-radius indices in index order (== top_k(-order) semantics),
// pads with the first hit. Early exit once 32 found.
// ---------------------------------------------------------------------------
__global__ __launch_bounds__(256) void ballq_kernel(const float* __restrict__ xyz,
                                                    const float* __restrict__ new_xyz,
                                                    int* __restrict__ idx_out) {
#pragma clang fp contract(off)
  const int lane = threadIdx.x & 63;
  const int gid  = blockIdx.x * 4 + (threadIdx.x >> 6);
  if (gid >= B_SZ * M_CENT) return;
  const int b = gid >> 11;  // / M_CENT
  const float* bx = xyz + (size_t)b * N_PTS * 3;
  const float cx = new_xyz[gid * 3 + 0];
  const float cy = new_xyz[gid * 3 + 1];
  const float cz = new_xyz[gid * 3 + 2];
  const float rr = (float)(0.8 * 0.8);  // double 0.64 -> f32 (JAX weak-scalar cast)
  int* out = idx_out + (size_t)gid * NSAMP;

  int count = 0;
  int first = -1;
  for (int base = 0; base < N_PTS; base += 64) {
    const int i = base + lane;
    const float dx = bx[i * 3 + 0] - cx;
    const float dy = bx[i * 3 + 1] - cy;
    const float dz = bx[i * 3 + 2] - cz;
    const float d = (dx * dx + dy * dy) + dz * dz;
    const bool pred = d < rr;
    const unsigned long long mk = __ballot(pred);
    if (pred) {
      const int slot = count + __popcll(mk & ((1ULL << lane) - 1ULL));
      if (slot < NSAMP) out[slot] = i;
    }
    if (first < 0 && mk != 0ULL) first = base + (__ffsll((long long)mk) - 1);
    count += __popcll(mk);
    if (count >= NSAMP) break;
  }
  if (count < NSAMP) {
    for (int k = count + lane; k < NSAMP; k += 64) out[k] = first;  // centroid itself is a hit
  }
}

// ---------------------------------------------------------------------------
// K3: gather + MLP(67->64 relu, 64->128 relu) + max over 32 samples.
// One 128-thread block per centroid. h0/h1 staged in LDS; reads are
// wave-uniform float4 broadcasts; weights coalesced from L1/L2.
// ---------------------------------------------------------------------------
__global__ __launch_bounds__(128) void mlp_kernel(const float* __restrict__ xyz,
                                                  const float* __restrict__ feats,
                                                  const float* __restrict__ new_xyz,
                                                  const int* __restrict__ idx,
                                                  const float* __restrict__ w1,
                                                  const float* __restrict__ b1,
                                                  const float* __restrict__ w2,
                                                  const float* __restrict__ b2,
                                                  float* __restrict__ out_feats) {
  const int gid = blockIdx.x;
  const int t   = threadIdx.x;
  const int b   = gid >> 11;  // / M_CENT

  __shared__ float h0[NSAMP * H0_STR];
  __shared__ float h1[NSAMP * H1_DIM];
  __shared__ int   sidx[NSAMP];

  if (t < NSAMP) sidx[t] = idx[(size_t)gid * NSAMP + t];
  const float cx = new_xyz[gid * 3 + 0];
  const float cy = new_xyz[gid * 3 + 1];
  const float cz = new_xyz[gid * 3 + 2];
  __syncthreads();

  const float* bxyz = xyz + (size_t)b * N_PTS * 3;
  const float* bft  = feats + (size_t)b * N_PTS * C_IN;
  for (int e = t; e < NSAMP * 67; e += 128) {
    const int s = e / 67;
    const int c = e - s * 67;
    const int p = sidx[s];
    float v;
    if (c < 3) {
      const float pc = bxyz[p * 3 + c];
      v = pc - (c == 0 ? cx : (c == 1 ? cy : cz));
    } else {
      v = bft[(size_t)p * C_IN + (c - 3)];
    }
    h0[s * H0_STR + c] = v;
  }
  __syncthreads();

  // layer 1: col = t&63 over H1_DIM, half = t>>6 picks 16 of 32 samples
  {
    const int col  = t & 63;
    const int half = t >> 6;
    float acc[16];
    const float bb = b1[col];
#pragma unroll
    for (int s = 0; s < 16; ++s) acc[s] = bb;
    const float* h0base = h0 + (half * 16) * H0_STR;
    for (int k = 0; k < 64; k += 4) {
      const float w0v = w1[(k + 0) * H1_DIM + col];
      const float w1v = w1[(k + 1) * H1_DIM + col];
      const float w2v = w1[(k + 2) * H1_DIM + col];
      const float w3v = w1[(k + 3) * H1_DIM + col];
#pragma unroll
      for (int s = 0; s < 16; ++s) {
        const float4 h4 = *reinterpret_cast<const float4*>(h0base + s * H0_STR + k);
        acc[s] += h4.x * w0v + h4.y * w1v + h4.z * w2v + h4.w * w3v;
      }
    }
    for (int k = 64; k < 67; ++k) {
      const float wv = w1[k * H1_DIM + col];
#pragma unroll
      for (int s = 0; s < 16; ++s) acc[s] += h0base[s * H0_STR + k] * wv;
    }
#pragma unroll
    for (int s = 0; s < 16; ++s) h1[(half * 16 + s) * H1_DIM + col] = fmaxf(acc[s], 0.0f);
  }
  __syncthreads();

  // layer 2 + max-pool: col = t over H2_DIM
  {
    float acc[32];
    const float bb = b2[t];
#pragma unroll
    for (int s = 0; s < 32; ++s) acc[s] = bb;
    for (int k = 0; k < 64; k += 4) {
      const float w0v = w2[(k + 0) * H2_DIM + t];
      const float w1v = w2[(k + 1) * H2_DIM + t];
      const float w2v = w2[(k + 2) * H2_DIM + t];
      const float w3v = w2[(k + 3) * H2_DIM + t];
#pragma unroll
      for (int s = 0; s < 32; ++s) {
        const float4 h4 = *reinterpret_cast<const float4*>(&h1[s * H1_DIM + k]);
        acc[s] += h4.x * w0v + h4.y * w1v + h4.z * w2v + h4.w * w3v;
      }
    }
    float mx = 0.0f;  // max(relu(v)) == max(0, max(v))
#pragma unroll
    for (int s = 0; s < 32; ++s) mx = fmaxf(mx, acc[s]);
    out_feats[(size_t)gid * H2_DIM + t] = mx;
  }
}

// ---------------------------------------------------------------------------
extern "C" void kernel_launch(void* const* d_in, const int* in_sizes, int n_in,
                              void* d_out, int out_size, void* d_ws, size_t ws_size,
                              hipStream_t stream) {
  const float* xyz   = (const float*)d_in[0];  // (4,16384,3) f32
  const float* feats = (const float*)d_in[1];  // (4,16384,64) f32
  // d_in[2] = bid (unused; output bid is all zeros)
  const float* w1 = (const float*)d_in[3];     // (67,64)
  const float* b1 = (const float*)d_in[4];     // (64,)
  const float* w2 = (const float*)d_in[5];     // (64,128)
  const float* b2 = (const float*)d_in[6];     // (128,)

  float* out       = (float*)d_out;
  float* out_xyz   = out;                                        // (4,2048,3)
  float* out_feats = out + (size_t)B_SZ * M_CENT * 3;            // (4,2048,128)
  float* out_bid   = out_feats + (size_t)B_SZ * M_CENT * H2_DIM; // (4,2048,1) int32 zeros
  int*   idx_ws    = (int*)d_ws;                                 // (4,2048,32) int32, 1 MiB

  hipLaunchKernelGGL(fps_kernel, dim3(B_SZ), dim3(FPS_T), 0, stream, xyz, out_xyz);
  hipLaunchKernelGGL(ballq_kernel, dim3((B_SZ * M_CENT + 3) / 4), dim3(256), 0, stream,
                     xyz, out_xyz, idx_ws);
  hipLaunchKernelGGL(mlp_kernel, dim3(B_SZ * M_CENT), dim3(128), 0, stream,
                     xyz, feats, out_xyz, idx_ws, w1, b1, w2, b2, out_feats);
  hipMemsetAsync(out_bid, 0, (size_t)B_SZ * M_CENT * sizeof(int), stream);
}

// Round 10
// 4551.919 us; speedup vs baseline: 1.3002x; 1.3002x over previous
//
#include <hip/hip_runtime.h>
#include <cstdint>
#include <cstddef>

#define B_SZ   4
#define N_PTS  16384
#define M_CENT 2048
#define NSAMP  32
#define C_IN   64
#define H1_DIM 64
#define H2_DIM 128
#define FPS_T  1024
#define NCL    256                // clusters of 64 points
#define NCELL  512                // 8x8x8 cells, Morton-coded
#define CKI(c) ((c) + ((c) >> 4)) // pad per-cluster arrays: stride-17 dwords
#define NCLP   (NCL + (NCL >> 4)) // 272 padded entries
#define H0_STR 68                 // 67 channels padded to 68 for 16B-aligned float4

// u64 max with neighbor fetched via DPP (invalid lanes keep self = identity
// under max). HW-verified rounds 3-9.
template <int CTRL>
__device__ __forceinline__ unsigned long long kmax_dpp(unsigned long long k) {
  const int lo  = (int)(unsigned)(k & 0xFFFFFFFFULL);
  const int hi  = (int)(unsigned)(k >> 32);
  const int olo = __builtin_amdgcn_update_dpp(lo, lo, CTRL, 0xF, 0xF, false);
  const int ohi = __builtin_amdgcn_update_dpp(hi, hi, CTRL, 0xF, 0xF, false);
  const unsigned long long o =
      ((unsigned long long)(unsigned)ohi << 32) | (unsigned)olo;
  return (o > k) ? o : k;
}

// Spread 3-bit value v to bits 0,3,6 (Morton part).
__device__ __forceinline__ int mpart(int v) {
  return (v & 1) | ((v & 2) << 2) | ((v & 4) << 4);
}

// ---------------------------------------------------------------------------
// K1: EXACT spatially-pruned FPS, v2. One 1024-thr block per batch.
// r9 post-mortem fixes (minimal diff from the PASSING r9 kernel):
//  (1) Morton cell order: r9's row-major cell sort made 64-pt clusters span
//      rows/columns in sparse regions -> rad 2-4 sigma -> ~100 clusters never
//      skippable (gap<0) -> F~100/iter, slower than brute force. Morton
//      (bit-interleaved 9-bit code, same 8^3 grid) makes sorted chunks cover
//      compact octree sub-blocks -> rad ~1-2 sigma -> F ~30-60.
//  (2) CKI padding (stride-17 dwords) on ckey/ccx/ccy/ccz/crad: r9's stride-16
//      u64 reads were 16-way bank conflicts (6.39M SQ_LDS_BANK_CONFLICT).
// Correctness unchanged: skips only when (dq-rad)^2 > ub with conservative
// margins (>> f32 eval error) -> skipped mins are provable identities ->
// pd and the u64 (dist, N-origidx) argmax stay bit-exact vs reference
// (max dist, min orig idx on tie). Sort order inside cells is atomic-
// nondeterministic -> only the skip PATTERN varies, outputs bit-exact.
// ---------------------------------------------------------------------------
__global__ __launch_bounds__(FPS_T, 4) void fps_kernel(const float* __restrict__ xyz,
                                                       float* __restrict__ out_xyz) {
#pragma clang fp contract(off)
  const int b    = blockIdx.x;
  const int t    = threadIdx.x;
  const int lane = t & 63;
  const int wave = t >> 6;           // 16 waves
  const float* bx = xyz + (size_t)b * N_PTS * 3;
  float* ox = out_xyz + (size_t)b * M_CENT * 3;

  __shared__ float              pd_l[N_PTS];       // 64K  running min-dist^2
  __shared__ unsigned short     sidx[N_PTS];       // 32K  sorted slot -> orig idx
  __shared__ float              ccx[NCLP];         // padded cluster centers (SoA)
  __shared__ float              ccy[NCLP];
  __shared__ float              ccz[NCLP];
  __shared__ float              crad_[NCLP];       // inflated radii
  __shared__ unsigned long long ckey[NCLP];        // exact cluster keys
  __shared__ int                hist[NCELL];
  __shared__ int                offs[NCELL];
  __shared__ unsigned long long s_key[2][16];
  __shared__ float              s_part[16][6];
  __shared__ float              s_bbox[6];

  // ---- preprocess 1: bounding box ----
  {
    float mnx = 1e30f, mny = 1e30f, mnz = 1e30f;
    float mxx = -1e30f, mxy = -1e30f, mxz = -1e30f;
    for (int i = t; i < N_PTS; i += FPS_T) {
      const float x = bx[i * 3 + 0], y = bx[i * 3 + 1], z = bx[i * 3 + 2];
      mnx = fminf(mnx, x); mxx = fmaxf(mxx, x);
      mny = fminf(mny, y); mxy = fmaxf(mxy, y);
      mnz = fminf(mnz, z); mxz = fmaxf(mxz, z);
    }
    for (int off = 32; off >= 1; off >>= 1) {
      mnx = fminf(mnx, __shfl_xor(mnx, off)); mxx = fmaxf(mxx, __shfl_xor(mxx, off));
      mny = fminf(mny, __shfl_xor(mny, off)); mxy = fmaxf(mxy, __shfl_xor(mxy, off));
      mnz = fminf(mnz, __shfl_xor(mnz, off)); mxz = fmaxf(mxz, __shfl_xor(mxz, off));
    }
    if (lane == 0) {
      s_part[wave][0] = mnx; s_part[wave][1] = mny; s_part[wave][2] = mnz;
      s_part[wave][3] = mxx; s_part[wave][4] = mxy; s_part[wave][5] = mxz;
    }
    __syncthreads();
    if (t == 0) {
      float v0 = 1e30f, v1 = 1e30f, v2 = 1e30f, v3 = -1e30f, v4 = -1e30f, v5 = -1e30f;
      for (int w = 0; w < 16; ++w) {
        v0 = fminf(v0, s_part[w][0]); v1 = fminf(v1, s_part[w][1]);
        v2 = fminf(v2, s_part[w][2]); v3 = fmaxf(v3, s_part[w][3]);
        v4 = fmaxf(v4, s_part[w][4]); v5 = fmaxf(v5, s_part[w][5]);
      }
      s_bbox[0] = v0; s_bbox[1] = v1; s_bbox[2] = v2;
      s_bbox[3] = 8.0f / fmaxf(v3 - v0, 1e-20f);   // inv widths
      s_bbox[4] = 8.0f / fmaxf(v4 - v1, 1e-20f);
      s_bbox[5] = 8.0f / fmaxf(v5 - v2, 1e-20f);
    }
    if (t < NCELL) hist[t] = 0;
    __syncthreads();
  }
  const float bb0 = s_bbox[0], bb1 = s_bbox[1], bb2 = s_bbox[2];
  const float iw0 = s_bbox[3], iw1 = s_bbox[4], iw2 = s_bbox[5];

  // ---- preprocess 2: histogram, prefix, scatter (counting sort by MORTON cell) ----
  for (int i = t; i < N_PTS; i += FPS_T) {
    const float x = bx[i * 3 + 0], y = bx[i * 3 + 1], z = bx[i * 3 + 2];
    int qx = (int)((x - bb0) * iw0); qx = qx > 7 ? 7 : qx;
    int qy = (int)((y - bb1) * iw1); qy = qy > 7 ? 7 : qy;
    int qz = (int)((z - bb2) * iw2); qz = qz > 7 ? 7 : qz;
    atomicAdd(&hist[(mpart(qx) << 2) | (mpart(qy) << 1) | mpart(qz)], 1);
  }
  __syncthreads();
  if (t < NCELL) {
    int s = 0;
    for (int i = 0; i < t; ++i) s += hist[i];
    offs[t] = s;
  }
  __syncthreads();
  for (int i = t; i < N_PTS; i += FPS_T) {
    const float x = bx[i * 3 + 0], y = bx[i * 3 + 1], z = bx[i * 3 + 2];
    int qx = (int)((x - bb0) * iw0); qx = qx > 7 ? 7 : qx;
    int qy = (int)((y - bb1) * iw1); qy = qy > 7 ? 7 : qy;
    int qz = (int)((z - bb2) * iw2); qz = qz > 7 ? 7 : qz;
    const int slot = atomicAdd(&offs[(mpart(qx) << 2) | (mpart(qy) << 1) | mpart(qz)], 1);
    sidx[slot] = (unsigned short)i;
  }
  for (int i = t; i < N_PTS; i += FPS_T) pd_l[i] = 1e10f;  // BIG
  __syncthreads();

  // ---- preprocess 3: cluster bounding spheres (wave w owns c == w mod 16) ----
  for (int c = wave; c < NCL; c += 16) {
    const int oi = (int)sidx[c * 64 + lane];
    const float x = bx[oi * 3 + 0], y = bx[oi * 3 + 1], z = bx[oi * 3 + 2];
    float mnx = x, mxx = x, mny = y, mxy = y, mnz = z, mxz = z;
    for (int off = 32; off >= 1; off >>= 1) {
      mnx = fminf(mnx, __shfl_xor(mnx, off)); mxx = fmaxf(mxx, __shfl_xor(mxx, off));
      mny = fminf(mny, __shfl_xor(mny, off)); mxy = fmaxf(mxy, __shfl_xor(mxy, off));
      mnz = fminf(mnz, __shfl_xor(mnz, off)); mxz = fmaxf(mxz, __shfl_xor(mxz, off));
    }
    const float ctx = (mnx + mxx) * 0.5f, cty = (mny + mxy) * 0.5f, ctz = (mnz + mxz) * 0.5f;
    const float ddx = x - ctx, ddy = y - cty, ddz = z - ctz;
    float dd = sqrtf(ddx * ddx + ddy * ddy + ddz * ddz);
    for (int off = 32; off >= 1; off >>= 1) dd = fmaxf(dd, __shfl_xor(dd, off));
    if (lane == 0) {
      const int ci = CKI(c);
      ccx[ci] = ctx; ccy[ci] = cty; ccz[ci] = ctz;
      crad_[ci] = dd * 1.0002f + 1e-6f;                  // conservative inflation
      ckey[ci]  = 0x501502F900000001ULL;                 // (bits(1e10)<<32)|1
    }
  }
  __syncthreads();

  // ---- main loop ----
  int cur = 0;  // reference idx0 = 0 (original index)
  for (int m = 0; m < M_CENT; ++m) {
    const int curs = __builtin_amdgcn_readfirstlane(cur);
    const float cx = bx[curs * 3 + 0];
    const float cy = bx[curs * 3 + 1];
    const float cz = bx[curs * 3 + 2];
    if (t == 0) { ox[m * 3 + 0] = cx; ox[m * 3 + 1] = cy; ox[m * 3 + 2] = cz; }
    if (m == M_CENT - 1) break;

    // Phase A: skip test, one cluster per lane (<16): c = lane*16 + wave
    // (own-slice: ckey[c] written only by this wave -> race-free, r9-proven)
    bool upd = false;
    if (lane < 16) {
      const int ci = CKI(lane * 16 + wave);
      const float qx = ccx[ci] - cx;
      const float qy = ccy[ci] - cy;
      const float qz = ccz[ci] - cz;
      const float dq  = sqrtf(qx * qx + qy * qy + qz * qz);
      const float gap = dq - crad_[ci];
      const float ub  = __uint_as_float((unsigned)(ckey[ci] >> 32));
      upd = !((gap > 0.0f) && (gap * gap > ub * 1.001f + 1e-5f));
    }
    unsigned long long mask = __ballot(upd);

    // Phase B: update flagged clusters (whole wave per cluster)
    while (mask) {
      const int s = __builtin_ctzll(mask);
      mask &= mask - 1;
      const int c    = s * 16 + wave;
      const int slot = c * 64 + lane;
      const int oi   = (int)sidx[slot];
      const float x = bx[oi * 3 + 0], y = bx[oi * 3 + 1], z = bx[oi * 3 + 2];
      const float dx = x - cx, dy = y - cy, dz = z - cz;
      const float d2 = (dx * dx + dy * dy) + dz * dz;   // numpy order, no FMA
      const float nd = fminf(pd_l[slot], d2);
      pd_l[slot] = nd;
      unsigned long long key = ((unsigned long long)__float_as_uint(nd) << 32)
                             | (unsigned int)(N_PTS - oi);
      key = kmax_dpp<0x111>(key);
      key = kmax_dpp<0x112>(key);
      key = kmax_dpp<0x114>(key);
      key = kmax_dpp<0x118>(key);
      key = kmax_dpp<0x142>(key);
      key = kmax_dpp<0x143>(key);
      if (lane == 63) ckey[CKI(c)] = key;
    }

    // Phase C: global argmax over 256 exact cluster keys.
    // Own-slice reduce (no barrier needed: slice written only by this wave).
    unsigned long long wk = (lane < 16) ? ckey[CKI(lane * 16 + wave)] : 0ULL;
    wk = kmax_dpp<0x111>(wk);
    wk = kmax_dpp<0x112>(wk);
    wk = kmax_dpp<0x114>(wk);
    wk = kmax_dpp<0x118>(wk);
    wk = kmax_dpp<0x142>(wk);
    wk = kmax_dpp<0x143>(wk);
    const int p = m & 1;
    if (lane == 63) s_key[p][wave] = wk;
    __syncthreads();
    unsigned long long k2 = s_key[p][lane & 15];
    k2 = kmax_dpp<0x111>(k2);
    k2 = kmax_dpp<0x112>(k2);
    k2 = kmax_dpp<0x114>(k2);
    k2 = kmax_dpp<0x118>(k2);
    const int lo15 = __builtin_amdgcn_readlane((int)(unsigned)(k2 & 0xFFFFFFFFULL), 15);
    cur = N_PTS - lo15;
  }
}

// ---------------------------------------------------------------------------
// K2: Ball query. One wave per centroid: ballot + prefix popcount appends the
// first 32 in-radius indices in index order (== top_k(-order) semantics),
// pads with the first hit. Early exit once 32 found.
// ---------------------------------------------------------------------------
__global__ __launch_bounds__(256) void ballq_kernel(const float* __restrict__ xyz,
                                                    const float* __restrict__ new_xyz,
                                                    int* __restrict__ idx_out) {
#pragma clang fp contract(off)
  const int lane = threadIdx.x & 63;
  const int gid  = blockIdx.x * 4 + (threadIdx.x >> 6);
  if (gid >= B_SZ * M_CENT) return;
  const int b = gid >> 11;  // / M_CENT
  const float* bx = xyz + (size_t)b * N_PTS * 3;
  const float cx = new_xyz[gid * 3 + 0];
  const float cy = new_xyz[gid * 3 + 1];
  const float cz = new_xyz[gid * 3 + 2];
  const float rr = (float)(0.8 * 0.8);  // double 0.64 -> f32 (JAX weak-scalar cast)
  int* out = idx_out + (size_t)gid * NSAMP;

  int count = 0;
  int first = -1;
  for (int base = 0; base < N_PTS; base += 64) {
    const int i = base + lane;
    const float dx = bx[i * 3 + 0] - cx;
    const float dy = bx[i * 3 + 1] - cy;
    const float dz = bx[i * 3 + 2] - cz;
    const float d = (dx * dx + dy * dy) + dz * dz;
    const bool pred = d < rr;
    const unsigned long long mk = __ballot(pred);
    if (pred) {
      const int slot = count + __popcll(mk & ((1ULL << lane) - 1ULL));
      if (slot < NSAMP) out[slot] = i;
    }
    if (first < 0 && mk != 0ULL) first = base + (__ffsll((long long)mk) - 1);
    count += __popcll(mk);
    if (count >= NSAMP) break;
  }
  if (count < NSAMP) {
    for (int k = count + lane; k < NSAMP; k += 64) out[k] = first;  // centroid itself is a hit
  }
}

// ---------------------------------------------------------------------------
// K3: gather + MLP(67->64 relu, 64->128 relu) + max over 32 samples.
// One 128-thread block per centroid. h0/h1 staged in LDS; reads are
// wave-uniform float4 broadcasts; weights coalesced from L1/L2.
// ---------------------------------------------------------------------------
__global__ __launch_bounds__(128) void mlp_kernel(const float* __restrict__ xyz,
                                                  const float* __restrict__ feats,
                                                  const float* __restrict__ new_xyz,
                                                  const int* __restrict__ idx,
                                                  const float* __restrict__ w1,
                                                  const float* __restrict__ b1,
                                                  const float* __restrict__ w2,
                                                  const float* __restrict__ b2,
                                                  float* __restrict__ out_feats) {
  const int gid = blockIdx.x;
  const int t   = threadIdx.x;
  const int b   = gid >> 11;  // / M_CENT

  __shared__ float h0[NSAMP * H0_STR];
  __shared__ float h1[NSAMP * H1_DIM];
  __shared__ int   sidx[NSAMP];

  if (t < NSAMP) sidx[t] = idx[(size_t)gid * NSAMP + t];
  const float cx = new_xyz[gid * 3 + 0];
  const float cy = new_xyz[gid * 3 + 1];
  const float cz = new_xyz[gid * 3 + 2];
  __syncthreads();

  const float* bxyz = xyz + (size_t)b * N_PTS * 3;
  const float* bft  = feats + (size_t)b * N_PTS * C_IN;
  for (int e = t; e < NSAMP * 67; e += 128) {
    const int s = e / 67;
    const int c = e - s * 67;
    const int p = sidx[s];
    float v;
    if (c < 3) {
      const float pc = bxyz[p * 3 + c];
      v = pc - (c == 0 ? cx : (c == 1 ? cy : cz));
    } else {
      v = bft[(size_t)p * C_IN + (c - 3)];
    }
    h0[s * H0_STR + c] = v;
  }
  __syncthreads();

  // layer 1: col = t&63 over H1_DIM, half = t>>6 picks 16 of 32 samples
  {
    const int col  = t & 63;
    const int half = t >> 6;
    float acc[16];
    const float bb = b1[col];
#pragma unroll
    for (int s = 0; s < 16; ++s) acc[s] = bb;
    const float* h0base = h0 + (half * 16) * H0_STR;
    for (int k = 0; k < 64; k += 4) {
      const float w0v = w1[(k + 0) * H1_DIM + col];
      const float w1v = w1[(k + 1) * H1_DIM + col];
      const float w2v = w1[(k + 2) * H1_DIM + col];
      const float w3v = w1[(k + 3) * H1_DIM + col];
#pragma unroll
      for (int s = 0; s < 16; ++s) {
        const float4 h4 = *reinterpret_cast<const float4*>(h0base + s * H0_STR + k);
        acc[s] += h4.x * w0v + h4.y * w1v + h4.z * w2v + h4.w * w3v;
      }
    }
    for (int k = 64; k < 67; ++k) {
      const float wv = w1[k * H1_DIM + col];
#pragma unroll
      for (int s = 0; s < 16; ++s) acc[s] += h0base[s * H0_STR + k] * wv;
    }
#pragma unroll
    for (int s = 0; s < 16; ++s) h1[(half * 16 + s) * H1_DIM + col] = fmaxf(acc[s], 0.0f);
  }
  __syncthreads();

  // layer 2 + max-pool: col = t over H2_DIM
  {
    float acc[32];
    const float bb = b2[t];
#pragma unroll
    for (int s = 0; s < 32; ++s) acc[s] = bb;
    for (int k = 0; k < 64; k += 4) {
      const float w0v = w2[(k + 0) * H2_DIM + t];
      const float w1v = w2[(k + 1) * H2_DIM + t];
      const float w2v = w2[(k + 2) * H2_DIM + t];
      const float w3v = w2[(k + 3) * H2_DIM + t];
#pragma unroll
      for (int s = 0; s < 32; ++s) {
        const float4 h4 = *reinterpret_cast<const float4*>(&h1[s * H1_DIM + k]);
        acc[s] += h4.x * w0v + h4.y * w1v + h4.z * w2v + h4.w * w3v;
      }
    }
    float mx = 0.0f;  // max(relu(v)) == max(0, max(v))
#pragma unroll
    for (int s = 0; s < 32; ++s) mx = fmaxf(mx, acc[s]);
    out_feats[(size_t)gid * H2_DIM + t] = mx;
  }
}

// ---------------------------------------------------------------------------
extern "C" void kernel_launch(void* const* d_in, const int* in_sizes, int n_in,
                              void* d_out, int out_size, void* d_ws, size_t ws_size,
                              hipStream_t stream) {
  const float* xyz   = (const float*)d_in[0];  // (4,16384,3) f32
  const float* feats = (const float*)d_in[1];  // (4,16384,64) f32
  // d_in[2] = bid (unused; output bid is all zeros)
  const float* w1 = (const float*)d_in[3];     // (67,64)
  const float* b1 = (const float*)d_in[4];     // (64,)
  const float* w2 = (const float*)d_in[5];     // (64,128)
  const float* b2 = (const float*)d_in[6];     // (128,)

  float* out       = (float*)d_out;
  float* out_xyz   = out;                                        // (4,2048,3)
  float* out_feats = out + (size_t)B_SZ * M_CENT * 3;            // (4,2048,128)
  float* out_bid   = out_feats + (size_t)B_SZ * M_CENT * H2_DIM; // (4,2048,1) int32 zeros
  int*   idx_ws    = (int*)d_ws;                                 // (4,2048,32) int32, 1 MiB

  hipLaunchKernelGGL(fps_kernel, dim3(B_SZ), dim3(FPS_T), 0, stream, xyz, out_xyz);
  hipLaunchKernelGGL(ballq_kernel, dim3((B_SZ * M_CENT + 3) / 4), dim3(256), 0, stream,
                     xyz, out_xyz, idx_ws);
  hipLaunchKernelGGL(mlp_kernel, dim3(B_SZ * M_CENT), dim3(128), 0, stream,
                     xyz, feats, out_xyz, idx_ws, w1, b1, w2, b2, out_feats);
  hipMemsetAsync(out_bid, 0, (size_t)B_SZ * M_CENT * sizeof(int), stream);
}